// Round 10
// baseline (141.125 us; speedup 1.0000x reference)
//
#include <hip/hip_runtime.h>

#define T_LEN 16384
#define NSEC 6                   // order-5 butter = 3 SOS each (hp+lp)
#define NSTATE 12
#define NMAT (NSTATE * NSTATE)   // 144
#define L_SMP 32                 // samples per thread
#define NPOW 6                   // M^(2^i), i=0..5, M = A^32
#define NTHR 512                 // 1 signal per block; 8 waves
#define NS_TOT 2048

// (A^32)^(2^i), i=0..5, fp32 (built in fp64 by k_matpow).
__device__ float g_Mp[NPOW * NMAT];
// Phi(t) = C * A^t, t=0..31 (row vectors), fp32.
__device__ float g_Phi[L_SMP * NSTATE];

__device__ __forceinline__ float rfl(float v) {
    return __int_as_float(__builtin_amdgcn_readfirstlane(__float_as_int(v)));
}

// ---------------------------------------------------------------------------
// Build one-step transition A (fp64); Phi(t)=C*A^t for t=0..31; square 10x,
// storing A^(2^it), it=5..10 as Mp[it-5] = (A^32)^(2^i), i=0..5.
// ---------------------------------------------------------------------------
__global__ void k_matpow(const float* __restrict__ sos) {
    __shared__ double A[NMAT];
    __shared__ double ph[2][NSTATE];
    int tid = threadIdx.x;

    if (tid < NSTATE) {
        double b0[NSEC], b1[NSEC], b2[NSEC], a1[NSEC], a2[NSEC];
#pragma unroll
        for (int i = 0; i < NSEC; ++i) {
            b0[i] = (double)sos[i * 6 + 0];
            b1[i] = (double)sos[i * 6 + 1];
            b2[i] = (double)sos[i * 6 + 2];
            a1[i] = (double)sos[i * 6 + 4];
            a2[i] = (double)sos[i * 6 + 5];
        }
        double w1[NSEC], w2[NSEC];
#pragma unroll
        for (int i = 0; i < NSEC; ++i) {
            w1[i] = (tid == 2 * i) ? 1.0 : 0.0;
            w2[i] = (tid == 2 * i + 1) ? 1.0 : 0.0;
        }
        double cur = 0.0;   // zero input: unit-state probe, one step
#pragma unroll
        for (int i = 0; i < NSEC; ++i) {
            double yv = fma(b0[i], cur, w1[i]);
            double n1 = fma(b1[i], cur, fma(-a1[i], yv, w2[i]));
            double n2 = fma(b2[i], cur, -(a2[i] * yv));
            w1[i] = n1; w2[i] = n2; cur = yv;
        }
#pragma unroll
        for (int i = 0; i < NSEC; ++i) {
            A[(2 * i) * NSTATE + tid]     = w1[i];   // column tid
            A[(2 * i + 1) * NSTATE + tid] = w2[i];
        }
        // C row: y(zero input) = sum_i w1_i * prod_{j>i} b0_j
        double c = 0.0;
        if ((tid & 1) == 0) {
            int i = tid >> 1;
            double p = 1.0;
            for (int j = i + 1; j < NSEC; ++j) p *= (double)sos[j * 6 + 0];
            c = p;
        }
        ph[0][tid] = c;
    }
    __syncthreads();

    // Phi(t) = C * A^t (row-vector iteration, double-buffered)
    for (int t = 0; t < L_SMP; ++t) {
        if (tid < NSTATE) {
            g_Phi[t * NSTATE + tid] = (float)ph[t & 1][tid];
            double v = 0.0;
#pragma unroll
            for (int kk = 0; kk < NSTATE; ++kk)
                v = fma(ph[t & 1][kk], A[kk * NSTATE + tid], v);
            ph[(t + 1) & 1][tid] = v;
        }
        __syncthreads();
    }

    const int rr = tid / NSTATE, cc = tid % NSTATE;
    for (int it = 1; it <= 10; ++it) {
        double v = 0.0;
        if (tid < NMAT) {
#pragma unroll
            for (int kk = 0; kk < NSTATE; ++kk)
                v = fma(A[rr * NSTATE + kk], A[kk * NSTATE + cc], v);
        }
        __syncthreads();
        if (tid < NMAT) {
            A[rr * NSTATE + cc] = v;
            if (it >= 5) g_Mp[(it - 5) * NMAT + tid] = (float)v;
        }
        __syncthreads();
    }
}

// In-place block-triangular matvec: v <- M*v (+ optional add handled by caller
// via ADD flag on the row result). M block-lower-triangular (biquad cascade):
// rows 2p,2p+1 read v[0..2p+1] only -> pair-descending in-place is safe.
// Row reads are float4 from LDS (broadcast, rows 48B-aligned).
#define TRI_MATVEC_IP(MBASE, V, EXTRA0, EXTRA1)                                 \
    {                                                                           \
        _Pragma("unroll")                                                       \
        for (int p = 5; p >= 0; --p) {                                          \
            float o0, o1;                                                       \
            _Pragma("unroll")                                                   \
            for (int rq = 0; rq < 2; ++rq) {                                    \
                const int q = 2 * p + rq;                                       \
                const float4* row = (const float4*)((MBASE) + q * NSTATE);      \
                float acc = (rq == 0 ? (EXTRA0) : (EXTRA1));                    \
                float4 r0 = row[0];                                             \
                acc = fmaf(r0.x, (V)[0], acc);                                  \
                acc = fmaf(r0.y, (V)[1], acc);                                  \
                if (p >= 1) { acc = fmaf(r0.z, (V)[2], acc);                    \
                              acc = fmaf(r0.w, (V)[3], acc); }                  \
                if (p >= 2) {                                                   \
                    float4 r1 = row[1];                                         \
                    acc = fmaf(r1.x, (V)[4], acc);                              \
                    acc = fmaf(r1.y, (V)[5], acc);                              \
                    if (p >= 3) { acc = fmaf(r1.z, (V)[6], acc);                \
                                  acc = fmaf(r1.w, (V)[7], acc); }              \
                }                                                               \
                if (p >= 4) {                                                   \
                    float4 r2 = row[2];                                         \
                    acc = fmaf(r2.x, (V)[8], acc);                              \
                    acc = fmaf(r2.y, (V)[9], acc);                              \
                    if (p >= 5) { acc = fmaf(r2.z, (V)[10], acc);               \
                                  acc = fmaf(r2.w, (V)[11], acc); }             \
                }                                                               \
                if (rq == 0) o0 = acc; else o1 = acc;                           \
            }                                                                   \
            (V)[2 * p] = o0; (V)[2 * p + 1] = o1;                               \
        }                                                                       \
    }

// ---------------------------------------------------------------------------
// One 512-thread block per signal. Thread t owns samples [t*32, t*32+32).
//   passA: zero-state filter; stash <- y_zs; c0 <- end state
//   scan : 6-round exact wave-local shuffle scan (M = A^32)
//   seed : si = excl_scan + M^lane * T_prevwave   (decay: only prev wave)
//   passB: y = y_zs + Phi(t)*si
//   write: 2 rounds x 32KB swizzled LDS staging -> coalesced stores
// ---------------------------------------------------------------------------
__global__ void __launch_bounds__(NTHR, 8)
k_main(const float* __restrict__ x, const float* __restrict__ sos,
       float* __restrict__ y) {
    __shared__ float Mp[NPOW][NMAT];     // 3.5 KB
    __shared__ float Ph[L_SMP * NSTATE]; // 1.5 KB
    __shared__ float cw[8][NSTATE];      // per-wave local totals
    __shared__ float4 sm4[2048];         // 32 KB write-stage buffer

    const int k = threadIdx.x;
    const int lane = k & 63;
    const int w = k >> 6;                // wave id 0..7
    const int sig = blockIdx.x;

    // stage scan matrices + Phi (overlaps pass A; barrier before scan)
    for (int i = k; i < NPOW * NMAT; i += NTHR)
        Mp[i / NMAT][i % NMAT] = g_Mp[i];
    for (int i = k; i < L_SMP * NSTATE; i += NTHR)
        Ph[i] = g_Phi[i];

    // coefficients -> SGPRs
    float b0[NSEC], b1[NSEC], b2[NSEC], a1[NSEC], a2[NSEC];
#pragma unroll
    for (int i = 0; i < NSEC; ++i) {
        b0[i] = rfl(sos[i * 6 + 0]);
        b1[i] = rfl(sos[i * 6 + 1]);
        b2[i] = rfl(sos[i * 6 + 2]);
        a1[i] = rfl(sos[i * 6 + 4]);
        a2[i] = rfl(sos[i * 6 + 5]);
    }

    // ---- pass A: zero-state filter; stash <- y_zs ----
    const float4* xp4 = (const float4*)(x + (size_t)sig * T_LEN) + k * (L_SMP / 4);
    float4 stash[L_SMP / 4];
    float w1_[NSEC], w2_[NSEC];
#pragma unroll
    for (int i = 0; i < NSEC; ++i) { w1_[i] = 0.f; w2_[i] = 0.f; }

    auto fstep = [&](float cur) -> float {
#pragma unroll
        for (int i = 0; i < NSEC; ++i) {
            float yv = fmaf(b0[i], cur, w1_[i]);
            w1_[i] = fmaf(b1[i], cur, fmaf(-a1[i], yv, w2_[i]));
            w2_[i] = fmaf(b2[i], cur, -(a2[i] * yv));
            cur = yv;
        }
        return cur;
    };

#pragma unroll
    for (int m = 0; m < L_SMP / 4; ++m) {
        float4 v = xp4[m];
        v.x = fstep(v.x); v.y = fstep(v.y); v.z = fstep(v.z); v.w = fstep(v.w);
        stash[m] = v;
    }
    float c0[NSTATE];
#pragma unroll
    for (int i = 0; i < NSEC; ++i) { c0[2 * i] = w1_[i]; c0[2 * i + 1] = w2_[i]; }

    __syncthreads();   // Mp/Ph staged

    // ---- wave-local inclusive scan: 6 shuffle rounds (exact in wave) ----
#pragma unroll
    for (int rnd = 0; rnd < NPOW; ++rnd) {
        const int d = 1 << rnd;
        float pr[NSTATE];
#pragma unroll
        for (int j = 0; j < NSTATE; ++j) pr[j] = __shfl_up(c0[j], d, 64);
        if (lane >= d) {
            TRI_MATVEC_IP(Mp[rnd], pr, c0[2 * p], c0[2 * p + 1]);
#pragma unroll
            for (int j = 0; j < NSTATE; ++j) c0[j] = pr[j];
        }
    }

    if (lane == 63) {
#pragma unroll
        for (int j = 0; j < NSTATE; ++j) cw[w][j] = c0[j];
    }
    __syncthreads();

    // ---- seed: si = exclusive scan; waves>0 add M^lane * T_prev ----
    float si[NSTATE];
#pragma unroll
    for (int j = 0; j < NSTATE; ++j) {
        si[j] = __shfl_up(c0[j], 1, 64);
        if (lane == 0) si[j] = 0.f;
    }
    if (w > 0) {
        float u[NSTATE];
#pragma unroll
        for (int j = 0; j < NSTATE; ++j) u[j] = cw[w - 1][j];
#pragma unroll
        for (int i = 0; i < NPOW; ++i) {
            if ((lane >> i) & 1) {
                TRI_MATVEC_IP(Mp[i], u, 0.f, 0.f);
            }
        }
#pragma unroll
        for (int j = 0; j < NSTATE; ++j) si[j] += u[j];
    }

    // ---- pass B: y = y_zs + Phi(t)*si (float4 LDS row reads, broadcast) ----
#pragma unroll
    for (int m = 0; m < L_SMP / 4; ++m) {
        float4 v = stash[m];
        float corr[4];
#pragma unroll
        for (int q = 0; q < 4; ++q) {
            const float4* ph = (const float4*)&Ph[(m * 4 + q) * NSTATE];
            float4 p0 = ph[0], p1 = ph[1], p2 = ph[2];
            float acc = p0.x * si[0];
            acc = fmaf(p0.y, si[1], acc);
            acc = fmaf(p0.z, si[2], acc);
            acc = fmaf(p0.w, si[3], acc);
            acc = fmaf(p1.x, si[4], acc);
            acc = fmaf(p1.y, si[5], acc);
            acc = fmaf(p1.z, si[6], acc);
            acc = fmaf(p1.w, si[7], acc);
            acc = fmaf(p2.x, si[8], acc);
            acc = fmaf(p2.y, si[9], acc);
            acc = fmaf(p2.z, si[10], acc);
            acc = fmaf(p2.w, si[11], acc);
            corr[q] = acc;
        }
        v.x += corr[0]; v.y += corr[1]; v.z += corr[2]; v.w += corr[3];
        stash[m] = v;
    }

    // ---- write staging: 2 rounds x 32KB, 8-f4-row XOR swizzle, coalesced ----
    float4* yp4 = (float4*)(y + (size_t)sig * T_LEN);
#pragma unroll 1
    for (int r = 0; r < 2; ++r) {
        __syncthreads();
        if ((k >> 8) == r) {
            const int t8 = k & 255;
#pragma unroll
            for (int m = 0; m < L_SMP / 4; ++m)
                sm4[t8 * 8 + (m ^ (t8 & 7))] = stash[m];
        }
        __syncthreads();
#pragma unroll
        for (int q = 0; q < 4; ++q) {
            int j = k + NTHR * q;                     // 0..2047
            int s = (j & ~7) | ((j ^ (j >> 3)) & 7);  // matches writer swizzle
            yp4[r * 2048 + j] = sm4[s];
        }
    }
}

extern "C" void kernel_launch(void* const* d_in, const int* in_sizes, int n_in,
                              void* d_out, int out_size, void* d_ws, size_t ws_size,
                              hipStream_t stream) {
    const float* x   = (const float*)d_in[0];
    const float* sos = (const float*)d_in[1];
    if (n_in >= 2 && in_sizes[0] <= 256 && in_sizes[1] > 256) {  // insurance
        x = (const float*)d_in[1];
        sos = (const float*)d_in[0];
    }
    float* out = (float*)d_out;

    int NS = out_size / T_LEN;      // 2048 signals
    if (NS > NS_TOT) NS = NS_TOT;
    if (NS < 1) NS = 1;

    k_matpow<<<1, 256, 0, stream>>>(sos);
    k_main<<<NS, NTHR, 0, stream>>>(x, sos, out);
}

// Round 11
// 107.499 us; speedup vs baseline: 1.3128x; 1.3128x over previous
//
#include <hip/hip_runtime.h>

#define T_LEN 16384
#define NSEC 6                   // order-5 butter = 3 SOS each (hp+lp)
#define NSTATE 12
#define NMAT (NSTATE * NSTATE)   // 144
#define L_SMP 32                 // samples per thread
#define NPOW 6                   // M^(2^i), i=0..5, M = A^32
#define NTHR 512                 // 1 signal per block; 8 waves
#define NS_TOT 2048

// (A^32)^(2^i), i=0..5, fp32 (built in fp64 by k_matpow).
__device__ float g_Mp[NPOW * NMAT];
// Phi(t) = C * A^t, t=0..31 (row vectors), fp32.
__device__ float g_Phi[L_SMP * NSTATE];

__device__ __forceinline__ float rfl(float v) {
    return __int_as_float(__builtin_amdgcn_readfirstlane(__float_as_int(v)));
}

// ---------------------------------------------------------------------------
// Build one-step transition A (fp64); Phi(t)=C*A^t for t=0..31; square 10x,
// storing A^(2^it), it=5..10 as Mp[it-5] = (A^32)^(2^i), i=0..5.
// ---------------------------------------------------------------------------
__global__ void k_matpow(const float* __restrict__ sos) {
    __shared__ double A[NMAT];
    __shared__ double ph[2][NSTATE];
    int tid = threadIdx.x;

    if (tid < NSTATE) {
        double b0[NSEC], b1[NSEC], b2[NSEC], a1[NSEC], a2[NSEC];
#pragma unroll
        for (int i = 0; i < NSEC; ++i) {
            b0[i] = (double)sos[i * 6 + 0];
            b1[i] = (double)sos[i * 6 + 1];
            b2[i] = (double)sos[i * 6 + 2];
            a1[i] = (double)sos[i * 6 + 4];
            a2[i] = (double)sos[i * 6 + 5];
        }
        double w1[NSEC], w2[NSEC];
#pragma unroll
        for (int i = 0; i < NSEC; ++i) {
            w1[i] = (tid == 2 * i) ? 1.0 : 0.0;
            w2[i] = (tid == 2 * i + 1) ? 1.0 : 0.0;
        }
        double cur = 0.0;   // zero input: unit-state probe, one step
#pragma unroll
        for (int i = 0; i < NSEC; ++i) {
            double yv = fma(b0[i], cur, w1[i]);
            double n1 = fma(b1[i], cur, fma(-a1[i], yv, w2[i]));
            double n2 = fma(b2[i], cur, -(a2[i] * yv));
            w1[i] = n1; w2[i] = n2; cur = yv;
        }
#pragma unroll
        for (int i = 0; i < NSEC; ++i) {
            A[(2 * i) * NSTATE + tid]     = w1[i];   // column tid
            A[(2 * i + 1) * NSTATE + tid] = w2[i];
        }
        // C row: y(zero input) = sum_i w1_i * prod_{j>i} b0_j
        double c = 0.0;
        if ((tid & 1) == 0) {
            int i = tid >> 1;
            double p = 1.0;
            for (int j = i + 1; j < NSEC; ++j) p *= (double)sos[j * 6 + 0];
            c = p;
        }
        ph[0][tid] = c;
    }
    __syncthreads();

    // Phi(t) = C * A^t (row-vector iteration, double-buffered)
    for (int t = 0; t < L_SMP; ++t) {
        if (tid < NSTATE) {
            g_Phi[t * NSTATE + tid] = (float)ph[t & 1][tid];
            double v = 0.0;
#pragma unroll
            for (int kk = 0; kk < NSTATE; ++kk)
                v = fma(ph[t & 1][kk], A[kk * NSTATE + tid], v);
            ph[(t + 1) & 1][tid] = v;
        }
        __syncthreads();
    }

    const int rr = tid / NSTATE, cc = tid % NSTATE;
    for (int it = 1; it <= 10; ++it) {
        double v = 0.0;
        if (tid < NMAT) {
#pragma unroll
            for (int kk = 0; kk < NSTATE; ++kk)
                v = fma(A[rr * NSTATE + kk], A[kk * NSTATE + cc], v);
        }
        __syncthreads();
        if (tid < NMAT) {
            A[rr * NSTATE + cc] = v;
            if (it >= 5) g_Mp[(it - 5) * NMAT + tid] = (float)v;
        }
        __syncthreads();
    }
}

// In-place block-triangular matvec: V <- M*V (+EXTRA row init). M is
// block-lower-triangular (biquad cascade); rows 2p,2p+1 read V[0..2p+1] only
// -> pair-descending in-place is safe. Rows read as float4 (LDS broadcast).
#define TRI_MATVEC_IP(MBASE, V, EXTRA0, EXTRA1)                                 \
    {                                                                           \
        _Pragma("unroll")                                                       \
        for (int p = 5; p >= 0; --p) {                                          \
            float o0, o1;                                                       \
            _Pragma("unroll")                                                   \
            for (int rq = 0; rq < 2; ++rq) {                                    \
                const int q = 2 * p + rq;                                       \
                const float4* row = (const float4*)((MBASE) + q * NSTATE);      \
                float acc = (rq == 0 ? (EXTRA0) : (EXTRA1));                    \
                float4 r0 = row[0];                                             \
                acc = fmaf(r0.x, (V)[0], acc);                                  \
                acc = fmaf(r0.y, (V)[1], acc);                                  \
                if (p >= 1) { acc = fmaf(r0.z, (V)[2], acc);                    \
                              acc = fmaf(r0.w, (V)[3], acc); }                  \
                if (p >= 2) {                                                   \
                    float4 r1 = row[1];                                         \
                    acc = fmaf(r1.x, (V)[4], acc);                              \
                    acc = fmaf(r1.y, (V)[5], acc);                              \
                    if (p >= 3) { acc = fmaf(r1.z, (V)[6], acc);                \
                                  acc = fmaf(r1.w, (V)[7], acc); }              \
                }                                                               \
                if (p >= 4) {                                                   \
                    float4 r2 = row[2];                                         \
                    acc = fmaf(r2.x, (V)[8], acc);                              \
                    acc = fmaf(r2.y, (V)[9], acc);                              \
                    if (p >= 5) { acc = fmaf(r2.z, (V)[10], acc);               \
                                  acc = fmaf(r2.w, (V)[11], acc); }             \
                }                                                               \
                if (rq == 0) o0 = acc; else o1 = acc;                           \
            }                                                                   \
            (V)[2 * p] = o0; (V)[2 * p + 1] = o1;                               \
        }                                                                       \
    }

// ---------------------------------------------------------------------------
// One 512-thread block per signal. Thread t owns samples [t*32, t*32+32).
//   load : 8 float4 global loads -> stash (issued FIRST; latency hides under
//          table staging + coeff setup)
//   passA: zero-state filter; stash <- y_zs; c0 <- end state
//   scan : 6-round exact wave-local shuffle scan (M = A^32)
//   seed : si = excl_scan + M^lane * T_prevwave  (A^2048 ~ 5e-7: truncate)
//   passB: y = y_zs + Phi(t)*si
//   write: 2 rounds x 32KB swizzled LDS staging -> coalesced stores
// launch_bounds(512,6): reg cap ~85 -> no spill (R10's (512,8)=64-cap spilled:
// WRITE_SIZE 262MB). 3 blocks/CU = 6 waves/SIMD.
// ---------------------------------------------------------------------------
__global__ void __launch_bounds__(NTHR, 6)
k_main(const float* __restrict__ x, const float* __restrict__ sos,
       float* __restrict__ y) {
    __shared__ float Mp[NPOW][NMAT];     // 3.5 KB
    __shared__ float Ph[L_SMP * NSTATE]; // 1.5 KB
    __shared__ float cw[8][NSTATE];      // per-wave local totals
    __shared__ float4 sm4[2048];         // 32 KB write-stage buffer

    const int k = threadIdx.x;
    const int lane = k & 63;
    const int w = k >> 6;                // wave id 0..7
    const int sig = blockIdx.x;

    // ---- front-loaded stash loads (HBM latency hides under staging below) ----
    const float4* xp4 = (const float4*)(x + (size_t)sig * T_LEN) + k * (L_SMP / 4);
    float4 stash[L_SMP / 4];
#pragma unroll
    for (int m = 0; m < L_SMP / 4; ++m) stash[m] = xp4[m];

    // stage scan matrices + Phi (L2-uniform, cheap)
    for (int i = k; i < NPOW * NMAT; i += NTHR)
        Mp[i / NMAT][i % NMAT] = g_Mp[i];
    for (int i = k; i < L_SMP * NSTATE; i += NTHR)
        Ph[i] = g_Phi[i];

    // coefficients -> SGPRs
    float b0[NSEC], b1[NSEC], b2[NSEC], a1[NSEC], a2[NSEC];
#pragma unroll
    for (int i = 0; i < NSEC; ++i) {
        b0[i] = rfl(sos[i * 6 + 0]);
        b1[i] = rfl(sos[i * 6 + 1]);
        b2[i] = rfl(sos[i * 6 + 2]);
        a1[i] = rfl(sos[i * 6 + 4]);
        a2[i] = rfl(sos[i * 6 + 5]);
    }

    // ---- pass A: zero-state filter; stash <- y_zs ----
    float w1_[NSEC], w2_[NSEC];
#pragma unroll
    for (int i = 0; i < NSEC; ++i) { w1_[i] = 0.f; w2_[i] = 0.f; }

    auto fstep = [&](float cur) -> float {
#pragma unroll
        for (int i = 0; i < NSEC; ++i) {
            float yv = fmaf(b0[i], cur, w1_[i]);
            w1_[i] = fmaf(b1[i], cur, fmaf(-a1[i], yv, w2_[i]));
            w2_[i] = fmaf(b2[i], cur, -(a2[i] * yv));
            cur = yv;
        }
        return cur;
    };

#pragma unroll
    for (int m = 0; m < L_SMP / 4; ++m) {
        float4 v = stash[m];
        v.x = fstep(v.x); v.y = fstep(v.y); v.z = fstep(v.z); v.w = fstep(v.w);
        stash[m] = v;
    }
    float c0[NSTATE];
#pragma unroll
    for (int i = 0; i < NSEC; ++i) { c0[2 * i] = w1_[i]; c0[2 * i + 1] = w2_[i]; }

    __syncthreads();   // Mp/Ph staged

    // ---- wave-local inclusive scan: 6 shuffle rounds (exact in wave) ----
#pragma unroll
    for (int rnd = 0; rnd < NPOW; ++rnd) {
        const int d = 1 << rnd;
        float pr[NSTATE];
#pragma unroll
        for (int j = 0; j < NSTATE; ++j) pr[j] = __shfl_up(c0[j], d, 64);
        if (lane >= d) {
            TRI_MATVEC_IP(Mp[rnd], pr, c0[2 * p], c0[2 * p + 1]);
#pragma unroll
            for (int j = 0; j < NSTATE; ++j) c0[j] = pr[j];
        }
    }

    if (lane == 63) {
#pragma unroll
        for (int j = 0; j < NSTATE; ++j) cw[w][j] = c0[j];
    }
    __syncthreads();

    // ---- seed: si = exclusive scan; waves>0 add M^lane * T_prev ----
    float si[NSTATE];
#pragma unroll
    for (int j = 0; j < NSTATE; ++j) {
        si[j] = __shfl_up(c0[j], 1, 64);
        if (lane == 0) si[j] = 0.f;
    }
    if (w > 0) {
        float u[NSTATE];
#pragma unroll
        for (int j = 0; j < NSTATE; ++j) u[j] = cw[w - 1][j];
#pragma unroll
        for (int i = 0; i < NPOW; ++i) {
            if ((lane >> i) & 1) {
                TRI_MATVEC_IP(Mp[i], u, 0.f, 0.f);
            }
        }
#pragma unroll
        for (int j = 0; j < NSTATE; ++j) si[j] += u[j];
    }

    // ---- pass B: y = y_zs + Phi(t)*si (float4 LDS row reads, broadcast) ----
#pragma unroll
    for (int m = 0; m < L_SMP / 4; ++m) {
        float4 v = stash[m];
        float corr[4];
#pragma unroll
        for (int q = 0; q < 4; ++q) {
            const float4* ph = (const float4*)&Ph[(m * 4 + q) * NSTATE];
            float4 p0 = ph[0], p1 = ph[1], p2 = ph[2];
            float acc = p0.x * si[0];
            acc = fmaf(p0.y, si[1], acc);
            acc = fmaf(p0.z, si[2], acc);
            acc = fmaf(p0.w, si[3], acc);
            acc = fmaf(p1.x, si[4], acc);
            acc = fmaf(p1.y, si[5], acc);
            acc = fmaf(p1.z, si[6], acc);
            acc = fmaf(p1.w, si[7], acc);
            acc = fmaf(p2.x, si[8], acc);
            acc = fmaf(p2.y, si[9], acc);
            acc = fmaf(p2.z, si[10], acc);
            acc = fmaf(p2.w, si[11], acc);
            corr[q] = acc;
        }
        v.x += corr[0]; v.y += corr[1]; v.z += corr[2]; v.w += corr[3];
        stash[m] = v;
    }

    // ---- write staging: 2 rounds x 32KB, 8-f4-row XOR swizzle, coalesced ----
    float4* yp4 = (float4*)(y + (size_t)sig * T_LEN);
#pragma unroll 1
    for (int r = 0; r < 2; ++r) {
        __syncthreads();
        if ((k >> 8) == r) {
            const int t8 = k & 255;
#pragma unroll
            for (int m = 0; m < L_SMP / 4; ++m)
                sm4[t8 * 8 + (m ^ (t8 & 7))] = stash[m];
        }
        __syncthreads();
#pragma unroll
        for (int q = 0; q < 4; ++q) {
            int j = k + NTHR * q;                     // 0..2047
            int s = (j & ~7) | ((j ^ (j >> 3)) & 7);  // matches writer swizzle
            yp4[r * 2048 + j] = sm4[s];
        }
    }
}

extern "C" void kernel_launch(void* const* d_in, const int* in_sizes, int n_in,
                              void* d_out, int out_size, void* d_ws, size_t ws_size,
                              hipStream_t stream) {
    const float* x   = (const float*)d_in[0];
    const float* sos = (const float*)d_in[1];
    if (n_in >= 2 && in_sizes[0] <= 256 && in_sizes[1] > 256) {  // insurance
        x = (const float*)d_in[1];
        sos = (const float*)d_in[0];
    }
    float* out = (float*)d_out;

    int NS = out_size / T_LEN;      // 2048 signals
    if (NS > NS_TOT) NS = NS_TOT;
    if (NS < 1) NS = 1;

    k_matpow<<<1, 256, 0, stream>>>(sos);
    k_main<<<NS, NTHR, 0, stream>>>(x, sos, out);
}